// Round 2
// baseline (125.174 us; speedup 1.0000x reference)
//
#include <hip/hip_runtime.h>
#include <math.h>

#define N_NODES 2048
#define IN_F 128
#define OUT_F 32
#define NEG_INF -9e15f

// XOR swizzle for p_s LDS word addressing: breaks the 512-word-stride bank
// aliasing between the 16 k-chunks in phase 3 (4-word granularity so float2/
// float4 accesses stay contiguous & aligned).
__device__ __forceinline__ int swz(int k) { return k ^ (((k >> 7) & 7) << 2); }

// ---------------------------------------------------------------------------
// Kernel A: Wh1 = h @ W[:128,:], Wh2 = h @ W[128:,:]  (both [N,32]),
//           Q[k] = 0.6 * sum_f a[f]*Wh2[k,f],  C[f] = 0.4*a[f].
// 8 nodes/block, 256 threads; thread (r=t>>5, f=t&31).
// ---------------------------------------------------------------------------
__global__ __launch_bounds__(256) void precompute_wh(
    const float* __restrict__ h, const float* __restrict__ W,
    const float* __restrict__ a,
    float* __restrict__ Wh1, float* __restrict__ Wh2,
    float* __restrict__ Q, float* __restrict__ C)
{
    __shared__ float h_s[8][IN_F];
    const int t = threadIdx.x;
    const int i0 = blockIdx.x * 8;

    // 8 rows * 128 f = 1024 floats = 256 float4, coalesced
    ((float4*)&h_s[0][0])[t] = ((const float4*)(h + (size_t)i0 * IN_F))[t];
    __syncthreads();

    const int f = t & 31;
    const int r = t >> 5;
    float acc1 = 0.f, acc2 = 0.f;
    #pragma unroll 8
    for (int c = 0; c < IN_F; ++c) {
        const float hv = h_s[r][c];
        acc1 = fmaf(hv, W[c * OUT_F + f], acc1);
        acc2 = fmaf(hv, W[(IN_F + c) * OUT_F + f], acc2);
    }
    Wh1[(i0 + r) * OUT_F + f] = acc1;
    Wh2[(i0 + r) * OUT_F + f] = acc2;

    // Q[k]: reduce 0.6*a_f*acc2 over the 32-lane f-group (xor offs <32 stay in group)
    float q = 0.6f * a[f] * acc2;
    #pragma unroll
    for (int off = 16; off > 0; off >>= 1) q += __shfl_xor(q, off, 64);
    if (f == 0) Q[i0 + r] = q;

    if (blockIdx.x == 0 && t < OUT_F) C[t] = 0.4f * a[t];
}

// ---------------------------------------------------------------------------
// Kernel B: TI=2 rows per block, 256 threads, grid 1024 (4 blocks/CU).
// Phase 1: s[i,k] = Q[k] + sum_f C[f]*|Wh1[i,f]+Wh2[k,f]| (2 VALU/(i,k,f)),
//          masked by adj; scores kept in registers.
// Phase 2: masked softmax (max/sum via xor-shuffle + LDS), p -> LDS (swizzled).
// Phase 3: h' = (p @ Wh1) / L, ELU epilogue. 2 f's per thread halves the
//          broadcast p-read instruction count; Wh1[k][f] reused for both rows.
// ---------------------------------------------------------------------------
__global__ __launch_bounds__(256, 4) void gat_row(
    const float* __restrict__ Wh1, const float* __restrict__ Wh2,
    const float* __restrict__ Q, const float* __restrict__ C,
    const int* __restrict__ adj, float* __restrict__ out)
{
    __shared__ float p_s[2 * N_NODES];        // 16 KB, swizzled word layout
    __shared__ float w1s[2][OUT_F];
    __shared__ float part[16][2][OUT_F];      // 4 KB phase-3 partials
    __shared__ float redA[4], redB[4], redC[4], redD[4];

    const int t = threadIdx.x;
    const int i0 = blockIdx.x * 2;

    if (t < 2 * OUT_F) w1s[t >> 5][t & 31] = Wh1[i0 * OUT_F + t];
    __syncthreads();

    const float4* w1f0 = (const float4*)&w1s[0][0];
    const float4* w1f1 = (const float4*)&w1s[1][0];

    // ---------------- Phase 1: scores (registers) ----------------
    float s00[4], s01[4], s10[4], s11[4];   // [kc]: (i0,k),(i0,k+1),(i0+1,k),(i0+1,k+1)
    float m0 = NEG_INF, m1 = NEG_INF;

    #pragma unroll
    for (int kc = 0; kc < 4; ++kc) {
        const int k = 2 * t + 512 * kc;     // consecutive k-pair per thread
        const float4* wr = (const float4*)(Wh2 + (size_t)k * OUT_F);
        float a00 = 0.f, a01 = 0.f, a10 = 0.f, a11 = 0.f;
        #pragma unroll
        for (int j = 0; j < 8; ++j) {
            const float4 w1a = w1f0[j];     // LDS broadcast (block-uniform)
            const float4 w1b = w1f1[j];
            const float4 qa = wr[j];        // Wh2 row k
            const float4 qb = wr[8 + j];    // Wh2 row k+1
            #pragma unroll
            for (int e = 0; e < 4; ++e) {
                const float cf  = C[4 * j + e];   // uniform -> SGPR
                const float w2a = (e==0)?qa.x:(e==1)?qa.y:(e==2)?qa.z:qa.w;
                const float w2b = (e==0)?qb.x:(e==1)?qb.y:(e==2)?qb.z:qb.w;
                const float w10 = (e==0)?w1a.x:(e==1)?w1a.y:(e==2)?w1a.z:w1a.w;
                const float w11 = (e==0)?w1b.x:(e==1)?w1b.y:(e==2)?w1b.z:w1b.w;
                a00 = fmaf(cf, fabsf(w10 + w2a), a00);   // add + fma(abs mod)
                a01 = fmaf(cf, fabsf(w10 + w2b), a01);
                a10 = fmaf(cf, fabsf(w11 + w2a), a10);
                a11 = fmaf(cf, fabsf(w11 + w2b), a11);
            }
        }
        const int2 ad0   = *(const int2*)(adj + (size_t)(i0 + 0) * N_NODES + k);
        const int2 ad1   = *(const int2*)(adj + (size_t)(i0 + 1) * N_NODES + k);
        const float2 qk  = *(const float2*)(Q + k);
        const float v00 = (ad0.x > 0) ? a00 + qk.x : NEG_INF;
        const float v01 = (ad0.y > 0) ? a01 + qk.y : NEG_INF;
        const float v10 = (ad1.x > 0) ? a10 + qk.x : NEG_INF;
        const float v11 = (ad1.y > 0) ? a11 + qk.y : NEG_INF;
        s00[kc] = v00; s01[kc] = v01; s10[kc] = v10; s11[kc] = v11;
        m0 = fmaxf(m0, fmaxf(v00, v01));
        m1 = fmaxf(m1, fmaxf(v10, v11));
    }

    // block max-reduce (xor-shuffle keeps result in every lane)
    #pragma unroll
    for (int off = 32; off > 0; off >>= 1) {
        m0 = fmaxf(m0, __shfl_xor(m0, off, 64));
        m1 = fmaxf(m1, __shfl_xor(m1, off, 64));
    }
    const int lane = t & 63, wid = t >> 6;
    if (lane == 0) { redA[wid] = m0; redB[wid] = m1; }
    __syncthreads();
    const float M0 = fmaxf(fmaxf(redA[0], redA[1]), fmaxf(redA[2], redA[3]));
    const float M1 = fmaxf(fmaxf(redB[0], redB[1]), fmaxf(redB[2], redB[3]));

    // ---------------- Phase 2: exp + p store + sum ----------------
    float l0 = 0.f, l1 = 0.f;
    #pragma unroll
    for (int kc = 0; kc < 4; ++kc) {
        const int k = 2 * t + 512 * kc;
        const float p00 = __expf(s00[kc] - M0);
        const float p01 = __expf(s01[kc] - M0);
        const float p10 = __expf(s10[kc] - M1);
        const float p11 = __expf(s11[kc] - M1);
        *(float2*)&p_s[swz(k)]           = make_float2(p00, p01);
        *(float2*)&p_s[N_NODES + swz(k)] = make_float2(p10, p11);
        l0 += p00 + p01;
        l1 += p10 + p11;
    }
    #pragma unroll
    for (int off = 32; off > 0; off >>= 1) {
        l0 += __shfl_xor(l0, off, 64);
        l1 += __shfl_xor(l1, off, 64);
    }
    if (lane == 0) { redC[wid] = l0; redD[wid] = l1; }
    __syncthreads();   // also orders p_s writes before phase-3 reads
    const float L0 = redC[0] + redC[1] + redC[2] + redC[3];
    const float L1 = redD[0] + redD[1] + redD[2] + redD[3];

    // ---------------- Phase 3: aggregate + ELU ----------------
    const int f2 = t & 15;          // covers f2 and f2+16
    const int c  = t >> 4;          // 16 chunks of 128 k
    float acc00 = 0.f, acc01 = 0.f, acc10 = 0.f, acc11 = 0.f;
    const int kb = c * 128;
    #pragma unroll 4
    for (int it = 0; it < 32; ++it) {
        const int k = kb + 4 * it;
        const float4 p0 = *(const float4*)&p_s[swz(k)];
        const float4 p1 = *(const float4*)&p_s[N_NODES + swz(k)];
        const float* wrow = Wh1 + (size_t)k * OUT_F + f2;
        const float wa0 = wrow[0],  wb0 = wrow[16];
        const float wa1 = wrow[32], wb1 = wrow[48];
        const float wa2 = wrow[64], wb2 = wrow[80];
        const float wa3 = wrow[96], wb3 = wrow[112];
        acc00 = fmaf(p0.x, wa0, acc00); acc01 = fmaf(p0.x, wb0, acc01);
        acc10 = fmaf(p1.x, wa0, acc10); acc11 = fmaf(p1.x, wb0, acc11);
        acc00 = fmaf(p0.y, wa1, acc00); acc01 = fmaf(p0.y, wb1, acc01);
        acc10 = fmaf(p1.y, wa1, acc10); acc11 = fmaf(p1.y, wb1, acc11);
        acc00 = fmaf(p0.z, wa2, acc00); acc01 = fmaf(p0.z, wb2, acc01);
        acc10 = fmaf(p1.z, wa2, acc10); acc11 = fmaf(p1.z, wb2, acc11);
        acc00 = fmaf(p0.w, wa3, acc00); acc01 = fmaf(p0.w, wb3, acc01);
        acc10 = fmaf(p1.w, wa3, acc10); acc11 = fmaf(p1.w, wb3, acc11);
    }
    part[c][0][f2]      = acc00;
    part[c][0][f2 + 16] = acc01;
    part[c][1][f2]      = acc10;
    part[c][1][f2 + 16] = acc11;
    __syncthreads();

    if (t < 2 * OUT_F) {
        const int ii = t >> 5, ff = t & 31;
        float s = 0.f;
        #pragma unroll
        for (int c2 = 0; c2 < 16; ++c2) s += part[c2][ii][ff];
        const float val = s / (ii == 0 ? L0 : L1);
        out[(i0 + ii) * OUT_F + ff] = (val > 0.f) ? val : (__expf(val) - 1.f);
    }
}

extern "C" void kernel_launch(void* const* d_in, const int* in_sizes, int n_in,
                              void* d_out, int out_size, void* d_ws, size_t ws_size,
                              hipStream_t stream) {
    const float* h   = (const float*)d_in[0];
    const int*   adj = (const int*)d_in[1];
    const float* W   = (const float*)d_in[2];
    const float* a   = (const float*)d_in[3];
    float* out = (float*)d_out;

    float* Wh1 = (float*)d_ws;                 // 2048*32
    float* Wh2 = Wh1 + N_NODES * OUT_F;        // 2048*32
    float* Q   = Wh2 + N_NODES * OUT_F;        // 2048
    float* C   = Q + N_NODES;                  // 32

    precompute_wh<<<N_NODES / 8, 256, 0, stream>>>(h, W, a, Wh1, Wh2, Q, C);
    gat_row<<<N_NODES / 2, 256, 0, stream>>>(Wh1, Wh2, Q, C, adj, out);
}

// Round 3
// 102.513 us; speedup vs baseline: 1.2211x; 1.2211x over previous
//
#include <hip/hip_runtime.h>
#include <math.h>

#define N_NODES 2048
#define IN_F 128
#define OUT_F 32
#define NEG_INF -9e15f

// XOR swizzle on 4-aligned LDS word index: toggles bits 2-4 by bits 7-9 so the
// 512-word-strided c-groups in phase 3 land on disjoint bank quads. Bijective,
// 16B-granular (float4-safe), consistent between phase-2 writes/phase-3 reads.
__device__ __forceinline__ int swz(int k) { return k ^ (((k >> 7) & 7) << 2); }

// ---------------------------------------------------------------------------
// Kernel A: Wh1[N][32] = h @ W[:128], Wh2T[32][N] = (h @ W[128:])^T,
//           Q[k] = 0.6*sum_f a[f]*Wh2[k,f], C[f] = 0.4*a[f].
// ---------------------------------------------------------------------------
__global__ __launch_bounds__(256) void precompute_wh(
    const float* __restrict__ h, const float* __restrict__ W,
    const float* __restrict__ a,
    float* __restrict__ Wh1, float* __restrict__ Wh2T,
    float* __restrict__ Q, float* __restrict__ C)
{
    __shared__ float h_s[8][IN_F];
    __shared__ float tr[8][OUT_F];
    const int t = threadIdx.x;
    const int i0 = blockIdx.x * 8;

    ((float4*)&h_s[0][0])[t] = ((const float4*)(h + (size_t)i0 * IN_F))[t];
    __syncthreads();

    const int f = t & 31;
    const int r = t >> 5;
    float acc1 = 0.f, acc2 = 0.f;
    #pragma unroll 8
    for (int c = 0; c < IN_F; ++c) {
        const float hv = h_s[r][c];
        acc1 = fmaf(hv, W[c * OUT_F + f], acc1);
        acc2 = fmaf(hv, W[(IN_F + c) * OUT_F + f], acc2);
    }
    Wh1[(i0 + r) * OUT_F + f] = acc1;
    tr[r][f] = acc2;

    // Q: reduce 0.6*a_f*acc2 over the 32-lane f-group
    float q = 0.6f * a[f] * acc2;
    #pragma unroll
    for (int off = 16; off > 0; off >>= 1) q += __shfl_xor(q, off, 64);
    if (f == 0) Q[i0 + r] = q;
    if (blockIdx.x == 0 && t < OUT_F) C[t] = 0.4f * a[t];

    __syncthreads();
    // transposed store of Wh2 via LDS (8-contiguous per f)
    const int f2 = t >> 3, r2 = t & 7;
    Wh2T[f2 * N_NODES + i0 + r2] = tr[r2][f2];
}

// ---------------------------------------------------------------------------
// Kernel B: TI=4 rows/block, 256 threads, grid 512.
// Phase 1: thread owns k-quads {4t, 1024+4t}; loops f reading Wh2T[f][..] as
//          lane-consecutive float4 (granule-perfect). 2 VALU per (i,k,f).
//          Scores stay in registers.
// Phase 2: masked softmax; p -> swizzled LDS.
// Phase 3: h' = (p @ Wh1)/L with 16-lane-coalesced Wh1 reads; ELU epilogue.
// ---------------------------------------------------------------------------
__global__ __launch_bounds__(256, 2) void gat_row(
    const float* __restrict__ Wh1, const float* __restrict__ Wh2T,
    const float* __restrict__ Q, const float* __restrict__ C,
    const int* __restrict__ adj, float* __restrict__ out)
{
    __shared__ float p_s[4][N_NODES];        // 32 KB
    __shared__ float w1s[4][OUT_F];
    __shared__ float part[16][4][OUT_F];     // 8 KB
    __shared__ float redM[4][4], redL[4][4];

    const int t = threadIdx.x;
    const int i0 = blockIdx.x * 4;

    if (t < 4 * OUT_F) w1s[t >> 5][t & 31] = Wh1[i0 * OUT_F + t];
    __syncthreads();

    const int kA = 4 * t;
    const int kB = N_NODES / 2 + 4 * t;

    // prefetch adj + Q (overlaps the f-loop)
    int4 adA[4], adB[4];
    #pragma unroll
    for (int i = 0; i < 4; ++i) {
        adA[i] = *(const int4*)(adj + (size_t)(i0 + i) * N_NODES + kA);
        adB[i] = *(const int4*)(adj + (size_t)(i0 + i) * N_NODES + kB);
    }
    const float4 QA = *(const float4*)(Q + kA);
    const float4 QB = *(const float4*)(Q + kB);

    // ---------------- Phase 1: scores ----------------
    float acc[4][8];
    #pragma unroll
    for (int i = 0; i < 4; ++i)
        #pragma unroll
        for (int s = 0; s < 8; ++s) acc[i][s] = 0.f;

    #pragma unroll 2
    for (int j = 0; j < 8; ++j) {
        float4 w1v[4];
        #pragma unroll
        for (int i = 0; i < 4; ++i) w1v[i] = *(const float4*)&w1s[i][4 * j];
        #pragma unroll
        for (int e = 0; e < 4; ++e) {
            const int f = 4 * j + e;
            const float cf = C[f];                                  // uniform -> sgpr
            const float4 wA = *(const float4*)(Wh2T + (size_t)f * N_NODES + kA);
            const float4 wB = *(const float4*)(Wh2T + (size_t)f * N_NODES + kB);
            #pragma unroll
            for (int i = 0; i < 4; ++i) {
                const float w1 = (e==0)?w1v[i].x:(e==1)?w1v[i].y:(e==2)?w1v[i].z:w1v[i].w;
                acc[i][0] = fmaf(cf, fabsf(w1 + wA.x), acc[i][0]);
                acc[i][1] = fmaf(cf, fabsf(w1 + wA.y), acc[i][1]);
                acc[i][2] = fmaf(cf, fabsf(w1 + wA.z), acc[i][2]);
                acc[i][3] = fmaf(cf, fabsf(w1 + wA.w), acc[i][3]);
                acc[i][4] = fmaf(cf, fabsf(w1 + wB.x), acc[i][4]);
                acc[i][5] = fmaf(cf, fabsf(w1 + wB.y), acc[i][5]);
                acc[i][6] = fmaf(cf, fabsf(w1 + wB.z), acc[i][6]);
                acc[i][7] = fmaf(cf, fabsf(w1 + wB.w), acc[i][7]);
            }
        }
    }

    // mask + add Q, per-i max
    float m[4];
    #pragma unroll
    for (int i = 0; i < 4; ++i) {
        acc[i][0] = (adA[i].x > 0) ? acc[i][0] + QA.x : NEG_INF;
        acc[i][1] = (adA[i].y > 0) ? acc[i][1] + QA.y : NEG_INF;
        acc[i][2] = (adA[i].z > 0) ? acc[i][2] + QA.z : NEG_INF;
        acc[i][3] = (adA[i].w > 0) ? acc[i][3] + QA.w : NEG_INF;
        acc[i][4] = (adB[i].x > 0) ? acc[i][4] + QB.x : NEG_INF;
        acc[i][5] = (adB[i].y > 0) ? acc[i][5] + QB.y : NEG_INF;
        acc[i][6] = (adB[i].z > 0) ? acc[i][6] + QB.z : NEG_INF;
        acc[i][7] = (adB[i].w > 0) ? acc[i][7] + QB.w : NEG_INF;
        float mm = fmaxf(fmaxf(fmaxf(acc[i][0], acc[i][1]), fmaxf(acc[i][2], acc[i][3])),
                         fmaxf(fmaxf(acc[i][4], acc[i][5]), fmaxf(acc[i][6], acc[i][7])));
        #pragma unroll
        for (int off = 32; off > 0; off >>= 1) mm = fmaxf(mm, __shfl_xor(mm, off, 64));
        m[i] = mm;
    }
    const int lane = t & 63, wid = t >> 6;
    if (lane == 0) {
        redM[0][wid] = m[0]; redM[1][wid] = m[1];
        redM[2][wid] = m[2]; redM[3][wid] = m[3];
    }
    __syncthreads();

    // ---------------- Phase 2: exp + p store + sum ----------------
    float L[4];
    #pragma unroll
    for (int i = 0; i < 4; ++i) {
        const float M = fmaxf(fmaxf(redM[i][0], redM[i][1]), fmaxf(redM[i][2], redM[i][3]));
        const float p0 = __expf(acc[i][0] - M);
        const float p1 = __expf(acc[i][1] - M);
        const float p2 = __expf(acc[i][2] - M);
        const float p3 = __expf(acc[i][3] - M);
        const float p4 = __expf(acc[i][4] - M);
        const float p5 = __expf(acc[i][5] - M);
        const float p6 = __expf(acc[i][6] - M);
        const float p7 = __expf(acc[i][7] - M);
        *(float4*)&p_s[i][swz(kA)] = make_float4(p0, p1, p2, p3);
        *(float4*)&p_s[i][swz(kB)] = make_float4(p4, p5, p6, p7);
        float ll = (p0 + p1) + (p2 + p3) + ((p4 + p5) + (p6 + p7));
        #pragma unroll
        for (int off = 32; off > 0; off >>= 1) ll += __shfl_xor(ll, off, 64);
        L[i] = ll;
    }
    if (lane == 0) {
        redL[0][wid] = L[0]; redL[1][wid] = L[1];
        redL[2][wid] = L[2]; redL[3][wid] = L[3];
    }
    __syncthreads();   // orders p_s + redL before phase 3

    // ---------------- Phase 3: aggregate + ELU ----------------
    const int f2 = t & 15;     // covers f2 and f2+16
    const int c  = t >> 4;     // 16 chunks of 128 k
    float a00=0.f, a01=0.f, a10=0.f, a11=0.f, a20=0.f, a21=0.f, a30=0.f, a31=0.f;
    const int kb = c * 128;
    #pragma unroll 4
    for (int it = 0; it < 32; ++it) {
        const int k = kb + 4 * it;
        const int ks = swz(k);
        const float4 p0 = *(const float4*)&p_s[0][ks];
        const float4 p1 = *(const float4*)&p_s[1][ks];
        const float4 p2 = *(const float4*)&p_s[2][ks];
        const float4 p3 = *(const float4*)&p_s[3][ks];
        const float* wrow = Wh1 + (size_t)k * OUT_F + f2;
        const float wa0 = wrow[0],  wb0 = wrow[16];
        const float wa1 = wrow[32], wb1 = wrow[48];
        const float wa2 = wrow[64], wb2 = wrow[80];
        const float wa3 = wrow[96], wb3 = wrow[112];
        a00 = fmaf(p0.x, wa0, a00); a01 = fmaf(p0.x, wb0, a01);
        a10 = fmaf(p1.x, wa0, a10); a11 = fmaf(p1.x, wb0, a11);
        a20 = fmaf(p2.x, wa0, a20); a21 = fmaf(p2.x, wb0, a21);
        a30 = fmaf(p3.x, wa0, a30); a31 = fmaf(p3.x, wb0, a31);
        a00 = fmaf(p0.y, wa1, a00); a01 = fmaf(p0.y, wb1, a01);
        a10 = fmaf(p1.y, wa1, a10); a11 = fmaf(p1.y, wb1, a11);
        a20 = fmaf(p2.y, wa1, a20); a21 = fmaf(p2.y, wb1, a21);
        a30 = fmaf(p3.y, wa1, a30); a31 = fmaf(p3.y, wb1, a31);
        a00 = fmaf(p0.z, wa2, a00); a01 = fmaf(p0.z, wb2, a01);
        a10 = fmaf(p1.z, wa2, a10); a11 = fmaf(p1.z, wb2, a11);
        a20 = fmaf(p2.z, wa2, a20); a21 = fmaf(p2.z, wb2, a21);
        a30 = fmaf(p3.z, wa2, a30); a31 = fmaf(p3.z, wb2, a31);
        a00 = fmaf(p0.w, wa3, a00); a01 = fmaf(p0.w, wb3, a01);
        a10 = fmaf(p1.w, wa3, a10); a11 = fmaf(p1.w, wb3, a11);
        a20 = fmaf(p2.w, wa3, a20); a21 = fmaf(p2.w, wb3, a21);
        a30 = fmaf(p3.w, wa3, a30); a31 = fmaf(p3.w, wb3, a31);
    }
    part[c][0][f2] = a00; part[c][0][f2 + 16] = a01;
    part[c][1][f2] = a10; part[c][1][f2 + 16] = a11;
    part[c][2][f2] = a20; part[c][2][f2 + 16] = a21;
    part[c][3][f2] = a30; part[c][3][f2 + 16] = a31;
    __syncthreads();

    if (t < 4 * OUT_F) {
        const int ii = t >> 5, ff = t & 31;
        float s = 0.f;
        #pragma unroll
        for (int c2 = 0; c2 < 16; ++c2) s += part[c2][ii][ff];
        const float Lf = redL[ii][0] + redL[ii][1] + redL[ii][2] + redL[ii][3];
        const float val = s / Lf;
        out[(i0 + ii) * OUT_F + ff] = (val > 0.f) ? val : (__expf(val) - 1.f);
    }
}

extern "C" void kernel_launch(void* const* d_in, const int* in_sizes, int n_in,
                              void* d_out, int out_size, void* d_ws, size_t ws_size,
                              hipStream_t stream) {
    const float* h   = (const float*)d_in[0];
    const int*   adj = (const int*)d_in[1];
    const float* W   = (const float*)d_in[2];
    const float* a   = (const float*)d_in[3];
    float* out = (float*)d_out;

    float* Wh1  = (float*)d_ws;                  // 2048*32
    float* Wh2T = Wh1 + N_NODES * OUT_F;         // 32*2048
    float* Q    = Wh2T + N_NODES * OUT_F;        // 2048
    float* C    = Q + N_NODES;                   // 32

    precompute_wh<<<N_NODES / 8, 256, 0, stream>>>(h, W, a, Wh1, Wh2T, Q, C);
    gat_row<<<N_NODES / 4, 256, 0, stream>>>(Wh1, Wh2T, Q, C, adj, out);
}

// Round 4
// 101.115 us; speedup vs baseline: 1.2379x; 1.0138x over previous
//
#include <hip/hip_runtime.h>
#include <math.h>

#define N_NODES 2048
#define IN_F 128
#define OUT_F 32
#define NEG_INF -9e15f
#define TI 8
#define NT 1024

// Swizzled word index for the p LDS buffer, layout [k_local][i] (8 floats/k,
// two float4 halves ih=0/1). S = ((k>>1)^(k>>4))&7 XORed into bits 2-4:
//  - phase-2 writes (k = 2*(t&511)+kp): 8-lane groups hit 8 distinct bank
//    quads (optimal for b128),
//  - phase-3 reads (k = 8c+it): the 8 c-groups/wave broadcast from 8 distinct
//    quads (fully conflict-free). Hand-verified for all it/c/kp combinations.
__device__ __forceinline__ int pw(int k, int ih) {
    const int S = ((k >> 1) ^ (k >> 4)) & 7;
    return ((k << 3) | (ih << 2)) ^ (S << 2);
}

// ---------------------------------------------------------------------------
// Kernel A: Wh1[N][32] = h @ W[:128], Wh2T[32][N] = (h @ W[128:])^T,
//           Q[k] = 0.6*sum_f a[f]*Wh2[k,f], C[f] = 0.4*a[f].
// (leakyrelu(x) = 0.6x + 0.4|x|; the per-row-i constant cancels in softmax.)
// ---------------------------------------------------------------------------
__global__ __launch_bounds__(256) void precompute_wh(
    const float* __restrict__ h, const float* __restrict__ W,
    const float* __restrict__ a,
    float* __restrict__ Wh1, float* __restrict__ Wh2T,
    float* __restrict__ Q, float* __restrict__ C)
{
    __shared__ float h_s[8][IN_F];
    __shared__ float tr[8][OUT_F];
    const int t = threadIdx.x;
    const int i0 = blockIdx.x * 8;

    ((float4*)&h_s[0][0])[t] = ((const float4*)(h + (size_t)i0 * IN_F))[t];
    __syncthreads();

    const int f = t & 31;
    const int r = t >> 5;
    float acc1 = 0.f, acc2 = 0.f;
    #pragma unroll 8
    for (int c = 0; c < IN_F; ++c) {
        const float hv = h_s[r][c];
        acc1 = fmaf(hv, W[c * OUT_F + f], acc1);
        acc2 = fmaf(hv, W[(IN_F + c) * OUT_F + f], acc2);
    }
    Wh1[(i0 + r) * OUT_F + f] = acc1;
    tr[r][f] = acc2;

    float q = 0.6f * a[f] * acc2;
    #pragma unroll
    for (int off = 16; off > 0; off >>= 1) q += __shfl_xor(q, off, 64);
    if (f == 0) Q[i0 + r] = q;
    if (blockIdx.x == 0 && t < OUT_F) C[t] = 0.4f * a[t];

    __syncthreads();
    const int f2 = t >> 3, r2 = t & 7;
    Wh2T[f2 * N_NODES + i0 + r2] = tr[r2][f2];
}

// ---------------------------------------------------------------------------
// Kernel B: TI=8 rows/block, 1024 threads, grid 256 (1 block/CU, 4 waves/SIMD).
// Phase 1: thread owns k-pair 2t; s[i,k] = Q[k] + sum_f C[f]*|Wh1[i,f]+Wh2[k,f]|
//          (add + fma-with-|src| = 2 VALU per (i,k,f)); scores in registers.
// Phase 2: masked softmax (shuffle + 2-level LDS reductions).
// Phase 3: two k-half passes through a 32 KB swizzled p buffer;
//          h' = (p @ Wh1)/L with coalesced float4 Wh1 loads; ELU epilogue.
// ---------------------------------------------------------------------------
__global__ __launch_bounds__(NT) void gat_row(
    const float* __restrict__ Wh1, const float* __restrict__ Wh2T,
    const float* __restrict__ Q, const float* __restrict__ C,
    const int* __restrict__ adj, float* __restrict__ out)
{
    __shared__ __align__(16) float p_s[8 * (N_NODES / 2)];   // 32 KB, one k-half
    __shared__ __align__(16) float w1s[TI][OUT_F];           // 1 KB
    __shared__ __align__(16) float part[16][TI][OUT_F];      // 16 KB
    __shared__ float redM[TI][16], redL[TI][16], Mfin[TI];

    const int t = threadIdx.x;
    const int i0 = blockIdx.x * TI;
    const int k0 = 2 * t;
    const int lane = t & 63, wid = t >> 6;

    if (t < TI * OUT_F) w1s[t >> 5][t & 31] = Wh1[i0 * OUT_F + t];
    __syncthreads();

    // prefetch adj + Q (long-latency HBM reads overlap the f-loop)
    int2 ad[TI];
    #pragma unroll
    for (int i = 0; i < TI; ++i)
        ad[i] = *(const int2*)(adj + (size_t)(i0 + i) * N_NODES + k0);
    const float2 q2 = *(const float2*)(Q + k0);

    // ---------------- Phase 1: scores ----------------
    float acc0[TI], acc1[TI];
    #pragma unroll
    for (int i = 0; i < TI; ++i) { acc0[i] = 0.f; acc1[i] = 0.f; }

    #pragma unroll 4
    for (int j = 0; j < 8; ++j) {
        float2 w2[4];
        #pragma unroll
        for (int e = 0; e < 4; ++e)
            w2[e] = *(const float2*)(Wh2T + (size_t)(4 * j + e) * N_NODES + k0);
        const float c0 = C[4 * j + 0], c1 = C[4 * j + 1];
        const float c2 = C[4 * j + 2], c3 = C[4 * j + 3];
        #pragma unroll
        for (int i = 0; i < TI; ++i) {
            const float4 w1 = *(const float4*)&w1s[i][4 * j];  // LDS broadcast
            float x;
            x = w1.x + w2[0].x; acc0[i] = fmaf(c0, fabsf(x), acc0[i]);
            x = w1.x + w2[0].y; acc1[i] = fmaf(c0, fabsf(x), acc1[i]);
            x = w1.y + w2[1].x; acc0[i] = fmaf(c1, fabsf(x), acc0[i]);
            x = w1.y + w2[1].y; acc1[i] = fmaf(c1, fabsf(x), acc1[i]);
            x = w1.z + w2[2].x; acc0[i] = fmaf(c2, fabsf(x), acc0[i]);
            x = w1.z + w2[2].y; acc1[i] = fmaf(c2, fabsf(x), acc1[i]);
            x = w1.w + w2[3].x; acc0[i] = fmaf(c3, fabsf(x), acc0[i]);
            x = w1.w + w2[3].y; acc1[i] = fmaf(c3, fabsf(x), acc1[i]);
        }
    }

    // mask + Q, per-i block max
    #pragma unroll
    for (int i = 0; i < TI; ++i) {
        acc0[i] = (ad[i].x > 0) ? acc0[i] + q2.x : NEG_INF;
        acc1[i] = (ad[i].y > 0) ? acc1[i] + q2.y : NEG_INF;
        float mm = fmaxf(acc0[i], acc1[i]);
        #pragma unroll
        for (int off = 32; off > 0; off >>= 1)
            mm = fmaxf(mm, __shfl_xor(mm, off, 64));
        if (lane == 0) redM[i][wid] = mm;
    }
    __syncthreads();
    if (t < 128) {          // level-2: i = t>>4, waves = t&15 (within one wave)
        float v = redM[t >> 4][t & 15];
        #pragma unroll
        for (int off = 8; off > 0; off >>= 1)
            v = fmaxf(v, __shfl_xor(v, off, 64));
        if ((t & 15) == 0) Mfin[t >> 4] = v;
    }
    __syncthreads();

    // ---------------- Phase 2: exp (p in registers) + L-reduce ----------------
    float pr0[TI], pr1[TI];
    #pragma unroll
    for (int i = 0; i < TI; ++i) {
        const float M = Mfin[i];
        pr0[i] = __expf(acc0[i] - M);
        pr1[i] = __expf(acc1[i] - M);
        float ll = pr0[i] + pr1[i];
        #pragma unroll
        for (int off = 32; off > 0; off >>= 1)
            ll += __shfl_xor(ll, off, 64);
        if (lane == 0) redL[i][wid] = ll;
    }

    // ---------------- Phase 3: two k-half passes ----------------
    const int fq = (t & 7) * 4;     // f quad
    const int c  = t >> 3;          // 0..127, 8 k per pass each
    float4 av[TI];
    #pragma unroll
    for (int i = 0; i < TI; ++i) av[i] = make_float4(0.f, 0.f, 0.f, 0.f);

    #pragma unroll
    for (int h = 0; h < 2; ++h) {
        __syncthreads();            // prior-pass p reads done / redL visible
        if ((t >> 9) == h) {        // this half's owners write p
            const int kl = 2 * (t & 511);
            *(float4*)&p_s[pw(kl, 0)]     = make_float4(pr0[0], pr0[1], pr0[2], pr0[3]);
            *(float4*)&p_s[pw(kl, 1)]     = make_float4(pr0[4], pr0[5], pr0[6], pr0[7]);
            *(float4*)&p_s[pw(kl + 1, 0)] = make_float4(pr1[0], pr1[1], pr1[2], pr1[3]);
            *(float4*)&p_s[pw(kl + 1, 1)] = make_float4(pr1[4], pr1[5], pr1[6], pr1[7]);
        }
        __syncthreads();
        #pragma unroll
        for (int it = 0; it < 8; ++it) {
            const int kl = 8 * c + it;
            const int kg = h * (N_NODES / 2) + kl;
            const float4 w  = *(const float4*)(Wh1 + (size_t)kg * OUT_F + fq);
            const float4 pA = *(const float4*)&p_s[pw(kl, 0)];
            const float4 pB = *(const float4*)&p_s[pw(kl, 1)];
            #define ACC(ii, pv) \
                av[ii].x = fmaf(pv, w.x, av[ii].x); \
                av[ii].y = fmaf(pv, w.y, av[ii].y); \
                av[ii].z = fmaf(pv, w.z, av[ii].z); \
                av[ii].w = fmaf(pv, w.w, av[ii].w);
            ACC(0, pA.x) ACC(1, pA.y) ACC(2, pA.z) ACC(3, pA.w)
            ACC(4, pB.x) ACC(5, pB.y) ACC(6, pB.z) ACC(7, pB.w)
            #undef ACC
        }
    }

    // reduce the 8 c-groups within each wave (c bits are lane bits 3-5)
    #pragma unroll
    for (int off = 8; off <= 32; off <<= 1) {
        #pragma unroll
        for (int i = 0; i < TI; ++i) {
            av[i].x += __shfl_xor(av[i].x, off, 64);
            av[i].y += __shfl_xor(av[i].y, off, 64);
            av[i].z += __shfl_xor(av[i].z, off, 64);
            av[i].w += __shfl_xor(av[i].w, off, 64);
        }
    }
    if (lane < 8) {                 // lanes 0-7 hold the wave's sums, fq = 4*lane
        #pragma unroll
        for (int i = 0; i < TI; ++i)
            *(float4*)&part[wid][i][fq] = av[i];
    }
    __syncthreads();

    // final cross-wave reduce + 1/L + ELU + store
    if (t < TI * OUT_F) {
        const int i = t >> 5, f = t & 31;
        float s = 0.f;
        #pragma unroll
        for (int w = 0; w < 16; ++w) s += part[w][i][f];
        float L = 0.f;
        #pragma unroll
        for (int w = 0; w < 16; ++w) L += redL[i][w];
        const float val = s / L;
        out[(i0 + i) * OUT_F + f] = (val > 0.f) ? val : (__expf(val) - 1.f);
    }
}

extern "C" void kernel_launch(void* const* d_in, const int* in_sizes, int n_in,
                              void* d_out, int out_size, void* d_ws, size_t ws_size,
                              hipStream_t stream) {
    const float* h   = (const float*)d_in[0];
    const int*   adj = (const int*)d_in[1];
    const float* W   = (const float*)d_in[2];
    const float* a   = (const float*)d_in[3];
    float* out = (float*)d_out;

    float* Wh1  = (float*)d_ws;                  // 2048*32
    float* Wh2T = Wh1 + N_NODES * OUT_F;         // 32*2048
    float* Q    = Wh2T + N_NODES * OUT_F;        // 2048
    float* C    = Q + N_NODES;                   // 32

    precompute_wh<<<N_NODES / 8, 256, 0, stream>>>(h, W, a, Wh1, Wh2T, Q, C);
    gat_row<<<N_NODES / TI, NT, 0, stream>>>(Wh1, Wh2T, Q, C, adj, out);
}